// Round 11
// baseline (5567.068 us; speedup 1.0000x reference)
//
#include <hip/hip_runtime.h>
#include <cstddef>

#define B_ 256
#define T_ 128
#define F_ 256
#define H_ 512
#define C_ 10

#define TEAMS 32     // teams; team owns BS batch rows
#define TB    16     // blocks per team; member owns NS output columns
#define BS    8      // batch rows per team
#define NS    32     // n columns per member block
#define LAG   2      // layer-1 trails layer-0 by LAG ticks

// ---------------------------------------------------------------------------
// GEMM (r9-proven): Cout[M,512] = A[M,K] @ W[512,K]^T + b1 + b2
// BM=BN=128, BK=16, 256 threads, 8x8 micro-tile.
// ---------------------------------------------------------------------------
template<int K>
__global__ __launch_bounds__(256, 2) void gemm_bias_kernel(
    const float* __restrict__ A, const float* __restrict__ W,
    const float* __restrict__ b1, const float* __restrict__ b2,
    float* __restrict__ Cout)
{
    __shared__ alignas(16) float As[16][132];
    __shared__ alignas(16) float Ws[16][132];

    const int tid = threadIdx.x;
    const int m0 = blockIdx.x * 128;
    const int n0 = blockIdx.y * 128;
    const int tx = tid & 15;
    const int ty = tid >> 4;

    float acc[8][8];
#pragma unroll
    for (int i = 0; i < 8; i++)
#pragma unroll
        for (int j = 0; j < 8; j++) acc[i][j] = 0.f;

    for (int k0 = 0; k0 < K; k0 += 16) {
#pragma unroll
        for (int i = 0; i < 2; i++) {
            int f = tid + 256 * i;
            int m = f >> 2, k4 = (f & 3) * 4;
            float4 v = *(const float4*)(A + (size_t)(m0 + m) * K + k0 + k4);
            As[k4 + 0][m] = v.x; As[k4 + 1][m] = v.y;
            As[k4 + 2][m] = v.z; As[k4 + 3][m] = v.w;
        }
#pragma unroll
        for (int i = 0; i < 2; i++) {
            int f = tid + 256 * i;
            int n = f >> 2, k4 = (f & 3) * 4;
            float4 v = *(const float4*)(W + (size_t)(n0 + n) * K + k0 + k4);
            Ws[k4 + 0][n] = v.x; Ws[k4 + 1][n] = v.y;
            Ws[k4 + 2][n] = v.z; Ws[k4 + 3][n] = v.w;
        }
        __syncthreads();

#pragma unroll
        for (int kk = 0; kk < 16; kk++) {
            float4 a0 = *(const float4*)&As[kk][ty * 8];
            float4 a1 = *(const float4*)&As[kk][ty * 8 + 4];
            float4 w0 = *(const float4*)&Ws[kk][tx * 8];
            float4 w1 = *(const float4*)&Ws[kk][tx * 8 + 4];
            float a[8] = {a0.x, a0.y, a0.z, a0.w, a1.x, a1.y, a1.z, a1.w};
            float w[8] = {w0.x, w0.y, w0.z, w0.w, w1.x, w1.y, w1.z, w1.w};
#pragma unroll
            for (int i = 0; i < 8; i++)
#pragma unroll
                for (int j = 0; j < 8; j++)
                    acc[i][j] = fmaf(a[i], w[j], acc[i][j]);
        }
        __syncthreads();
    }

    float bias[8];
#pragma unroll
    for (int j = 0; j < 8; j++) {
        int n = n0 + tx * 8 + j;
        bias[j] = b1[n] + b2[n];
    }
#pragma unroll
    for (int i = 0; i < 8; i++) {
        int m = m0 + ty * 8 + i;
        float4 v0 = {acc[i][0] + bias[0], acc[i][1] + bias[1],
                     acc[i][2] + bias[2], acc[i][3] + bias[3]};
        float4 v1 = {acc[i][4] + bias[4], acc[i][5] + bias[5],
                     acc[i][6] + bias[6], acc[i][7] + bias[7]};
        *(float4*)(Cout + (size_t)m * H_ + n0 + tx * 8)     = v0;
        *(float4*)(Cout + (size_t)m * H_ + n0 + tx * 8 + 4) = v1;
    }
}

// ---------------------------------------------------------------------------
// Fused two-layer scan, t-pipelined (LAG=2). Structure identical to r10
// (correctness-proven: passed, absmax 7.6e-6). Per tick tau:
//   L0 (t=tau):    h0(t)  = relu(proj0(t) + Whh0 h0(t-1))
//   L1 (t1=tau-2): h1(t1) = relu(Wih1 h0(t1) + Whh1 h1(t1-1) + biases)
//
// Round-11 register-plan fix (r10 spilled 2.2 GB to scratch):
//  * ONLY Whh0 slice is register-pinned (16 float4 = r9-proven footprint).
//  * Wih1/Whh1 slices are STREAMED from L2 each tick: 16 float4 loaded into
//    transient regs right before each L1 j-loop (peak live ~175 regs, fits
//    the 256 VGPR+AGPR budget -> no memory spill). LLVM LICM cannot hoist
//    relaxed-atomic loads (monotonic != unordered), so they stay per-tick.
//    L2 cost ~128 KB/block/tick ~ 0.3 us/tick/XCD, hidden under compute.
//
// Transport/sync: r4/r5/r7/r9/r10-proven (relaxed agent atomics on data,
// vmcnt(0)-drain via __syncthreads before signal, monotonic fetch_add
// counters in 64 B-per-team lines).
// ---------------------------------------------------------------------------
__global__ __launch_bounds__(256, 2) void fused_scan_kernel(
    float* __restrict__ h0d, float* __restrict__ h1d,
    const float* __restrict__ Whh0, const float* __restrict__ Wih1,
    const float* __restrict__ Whh1,
    const float* __restrict__ bih1, const float* __restrict__ bhh1,
    unsigned int* __restrict__ bar)
{
    __shared__ alignas(16) float hs0a[BS][H_];   // 16 KB: L0 recurrent input
    __shared__ alignas(16) float hs0b[BS][H_];   // 16 KB: L1 input h0(t1)
    __shared__ alignas(16) float hs1[BS][H_];    // 16 KB: L1 recurrent input
    float (*red0)[BS][NS] = (float (*)[BS][NS])&hs0b[0][0];  // alias (timed ok)
    float (*red1)[BS][NS] = (float (*)[BS][NS])&hs0a[0][0];  // alias (timed ok)

    const int tid  = threadIdx.x;
    const int team = blockIdx.x & 31;
    const int mem  = blockIdx.x >> 5;
    const int b0   = team * BS;
    const int n0   = mem * NS;
    const int nl2  = tid & 15;          // col-pair: cols n0+2*nl2, +1
    const int kg   = tid >> 4;          // 0..15, k-slice of 32
    const int n    = n0 + nl2 * 2;

    unsigned int* cntL0 = bar + team * 16;          // 64 B line per team
    unsigned int* cntL1 = bar + TEAMS * 16 + team * 16;

    const size_t r0 = (size_t)n * H_ + (size_t)kg * 32;
    const size_t r1 = (size_t)(n + 1) * H_ + (size_t)kg * 32;

    auto loadW = [](const float* base, float4* dst) {
        const unsigned long long* q = (const unsigned long long*)base;
#pragma unroll
        for (int j = 0; j < 8; j++) {
            union { unsigned long long u[2]; float4 f; } v;
            v.u[0] = __hip_atomic_load(q + 2 * j,     __ATOMIC_RELAXED,
                                       __HIP_MEMORY_SCOPE_AGENT);
            v.u[1] = __hip_atomic_load(q + 2 * j + 1, __ATOMIC_RELAXED,
                                       __HIP_MEMORY_SCOPE_AGENT);
            dst[j] = v.f;
        }
    };

    // ---- ONLY Whh0 pinned (r9-proven 16-float4 footprint) ----
    float4 wA0[8], wA1[8];
    loadW(Whh0 + r0, wA0); loadW(Whh0 + r1, wA1);

    const int bb = tid >> 5, n2 = tid & 31;         // epilogue mapping
    float* p0ptr = h0d + ((size_t)(b0 + bb) * T_) * H_ + n0 + n2;
    float* p1ptr = h1d + ((size_t)(b0 + bb) * T_) * H_ + n0 + n2;
    float projv  = *p0ptr;                           // proj0(0) prefetch
    const float bias1 = bih1[n0 + n2] + bhh1[n0 + n2];

    for (int tau = 0; tau < T_ + LAG; tau++) {
        // ================= layer 0: step t = tau =================
        if (tau < T_) {
            const int t = tau;
            if (t > 0 && tid == 0) {
                const unsigned tgt = (unsigned)(TB * t);
                while (__hip_atomic_load(cntL0, __ATOMIC_RELAXED,
                                         __HIP_MEMORY_SCOPE_AGENT) < tgt)
                    __builtin_amdgcn_s_sleep(2);
            }
            __syncthreads();                              // (A)
            if (t == 0) {
#pragma unroll
                for (int i = 0; i < 4; i++)
                    ((float4*)hs0a)[tid + 256 * i] = float4{0.f, 0.f, 0.f, 0.f};
            } else {
                const float* sp = h0d + ((size_t)b0 * T_ + (t - 1)) * H_;
#pragma unroll
                for (int b = 0; b < BS; b++) {
                    unsigned long long v = __hip_atomic_load(
                        (const unsigned long long*)(sp + (size_t)b * T_ * H_) + tid,
                        __ATOMIC_RELAXED, __HIP_MEMORY_SCOPE_AGENT);
                    *((unsigned long long*)&hs0a[b][0] + tid) = v;
                }
            }
            __syncthreads();                              // (B)

            float p0[BS], p1[BS];
#pragma unroll
            for (int b = 0; b < BS; b++) { p0[b] = 0.f; p1[b] = 0.f; }
#pragma unroll
            for (int j = 0; j < 8; j++) {
                const float4 wa = wA0[j], wb = wA1[j];
                const int kb = kg * 32 + j * 4;
#pragma unroll
                for (int b = 0; b < BS; b++) {
                    float4 hv = *(const float4*)&hs0a[b][kb];
                    p0[b] = fmaf(wa.x, hv.x, fmaf(wa.y, hv.y,
                            fmaf(wa.z, hv.z, fmaf(wa.w, hv.w, p0[b]))));
                    p1[b] = fmaf(wb.x, hv.x, fmaf(wb.y, hv.y,
                            fmaf(wb.z, hv.z, fmaf(wb.w, hv.w, p1[b]))));
                }
            }
#pragma unroll
            for (int b = 0; b < BS; b++)
                *(float2*)&red0[kg][b][nl2 * 2] = float2{p0[b], p1[b]};
            __syncthreads();                              // (C)
            {
                float s = 0.f;
#pragma unroll
                for (int g = 0; g < 16; g++) s += red0[g][bb][n2];
                float h = fmaxf(s + projv, 0.f);
                __hip_atomic_store(p0ptr, h,
                                   __ATOMIC_RELAXED, __HIP_MEMORY_SCOPE_AGENT);
            }
            p0ptr += H_;
            if (t + 1 < T_) projv = *p0ptr;               // next proj0 in flight
            __syncthreads();                              // (D) drain h0 stores
            if (tid == 0)
                __hip_atomic_fetch_add(cntL0, 1u,
                                       __ATOMIC_RELAXED, __HIP_MEMORY_SCOPE_AGENT);
        }

        // ================= layer 1: step t1 = tau - LAG =================
        const int t1 = tau - LAG;
        if (t1 >= 0) {
            if (tid == 0) {
                const unsigned tgt0 = (unsigned)(TB * (t1 + 1));
                while (__hip_atomic_load(cntL0, __ATOMIC_RELAXED,
                                         __HIP_MEMORY_SCOPE_AGENT) < tgt0)
                    __builtin_amdgcn_s_sleep(2);
                if (t1 > 0) {
                    const unsigned tgt1 = (unsigned)(TB * t1);
                    while (__hip_atomic_load(cntL1, __ATOMIC_RELAXED,
                                             __HIP_MEMORY_SCOPE_AGENT) < tgt1)
                        __builtin_amdgcn_s_sleep(2);
                }
            }
            __syncthreads();                              // (E)
            {
                const float* sp = h0d + ((size_t)b0 * T_ + t1) * H_;
#pragma unroll
                for (int b = 0; b < BS; b++) {
                    unsigned long long v = __hip_atomic_load(
                        (const unsigned long long*)(sp + (size_t)b * T_ * H_) + tid,
                        __ATOMIC_RELAXED, __HIP_MEMORY_SCOPE_AGENT);
                    *((unsigned long long*)&hs0b[b][0] + tid) = v;
                }
            }
            if (t1 == 0) {
#pragma unroll
                for (int i = 0; i < 4; i++)
                    ((float4*)hs1)[tid + 256 * i] = float4{0.f, 0.f, 0.f, 0.f};
            } else {
                const float* sp = h1d + ((size_t)b0 * T_ + (t1 - 1)) * H_;
#pragma unroll
                for (int b = 0; b < BS; b++) {
                    unsigned long long v = __hip_atomic_load(
                        (const unsigned long long*)(sp + (size_t)b * T_ * H_) + tid,
                        __ATOMIC_RELAXED, __HIP_MEMORY_SCOPE_AGENT);
                    *((unsigned long long*)&hs1[b][0] + tid) = v;
                }
            }
            __syncthreads();                              // (F)

            float q0[BS], q1[BS];
#pragma unroll
            for (int b = 0; b < BS; b++) { q0[b] = 0.f; q1[b] = 0.f; }
            {
                float4 wB0[8], wB1[8];                    // streamed this tick
                loadW(Wih1 + r0, wB0); loadW(Wih1 + r1, wB1);
#pragma unroll
                for (int j = 0; j < 8; j++) {             // input proj: Wih1·h0
                    const float4 wa = wB0[j], wb = wB1[j];
                    const int kb = kg * 32 + j * 4;
#pragma unroll
                    for (int b = 0; b < BS; b++) {
                        float4 hv = *(const float4*)&hs0b[b][kb];
                        q0[b] = fmaf(wa.x, hv.x, fmaf(wa.y, hv.y,
                                fmaf(wa.z, hv.z, fmaf(wa.w, hv.w, q0[b]))));
                        q1[b] = fmaf(wb.x, hv.x, fmaf(wb.y, hv.y,
                                fmaf(wb.z, hv.z, fmaf(wb.w, hv.w, q1[b]))));
                    }
                }
            }
            {
                float4 wC0[8], wC1[8];                    // streamed this tick
                loadW(Whh1 + r0, wC0); loadW(Whh1 + r1, wC1);
#pragma unroll
                for (int j = 0; j < 8; j++) {             // recurrent: Whh1·h1
                    const float4 wa = wC0[j], wb = wC1[j];
                    const int kb = kg * 32 + j * 4;
#pragma unroll
                    for (int b = 0; b < BS; b++) {
                        float4 hv = *(const float4*)&hs1[b][kb];
                        q0[b] = fmaf(wa.x, hv.x, fmaf(wa.y, hv.y,
                                fmaf(wa.z, hv.z, fmaf(wa.w, hv.w, q0[b]))));
                        q1[b] = fmaf(wb.x, hv.x, fmaf(wb.y, hv.y,
                                fmaf(wb.z, hv.z, fmaf(wb.w, hv.w, q1[b]))));
                    }
                }
            }
#pragma unroll
            for (int b = 0; b < BS; b++)
                *(float2*)&red1[kg][b][nl2 * 2] = float2{q0[b], q1[b]};
            __syncthreads();                              // (G)
            {
                float s = 0.f;
#pragma unroll
                for (int g = 0; g < 16; g++) s += red1[g][bb][n2];
                float h = fmaxf(s + bias1, 0.f);
                __hip_atomic_store(p1ptr, h,
                                   __ATOMIC_RELAXED, __HIP_MEMORY_SCOPE_AGENT);
            }
            p1ptr += H_;
            __syncthreads();                              // (H) drain h1 stores
            if (tid == 0)
                __hip_atomic_fetch_add(cntL1, 1u,
                                       __ATOMIC_RELAXED, __HIP_MEMORY_SCOPE_AGENT);
        }
    }
}

// ---------------------------------------------------------------------------
// FC head: out[b][c] = sum_i h1[b][i] * Wfc[c][i] + bfc[c]
// ---------------------------------------------------------------------------
__global__ __launch_bounds__(256) void fc_kernel(
    const float* __restrict__ Hl, const float* __restrict__ Wfc,
    const float* __restrict__ bfc, float* __restrict__ out)
{
    const int b = blockIdx.x;
    const int tid = threadIdx.x;
    const float* hb = Hl + (size_t)b * (T_ * H_);

    float acc[C_];
#pragma unroll
    for (int c = 0; c < C_; c++) acc[c] = 0.f;

    for (int i = tid * 4; i < T_ * H_; i += 256 * 4) {
        float4 hv = *(const float4*)(hb + i);
#pragma unroll
        for (int c = 0; c < C_; c++) {
            float4 wv = *(const float4*)(Wfc + (size_t)c * (T_ * H_) + i);
            acc[c] = fmaf(hv.x, wv.x, fmaf(hv.y, wv.y,
                     fmaf(hv.z, wv.z, fmaf(hv.w, wv.w, acc[c]))));
        }
    }

    __shared__ float red[4][C_];
#pragma unroll
    for (int c = 0; c < C_; c++) {
        float v = acc[c];
#pragma unroll
        for (int off = 32; off >= 1; off >>= 1) v += __shfl_xor(v, off, 64);
        if ((tid & 63) == 0) red[tid >> 6][c] = v;
    }
    __syncthreads();
    if (tid < C_) {
        float v = red[0][tid] + red[1][tid] + red[2][tid] + red[3][tid] + bfc[tid];
        out[(size_t)b * C_ + tid] = v;
    }
}

// ---------------------------------------------------------------------------
// Pipeline: proj0 GEMM -> fused(scan0 + proj1-on-the-fly + scan1) -> FC.
// Counters: cntL0[32] + cntL1[32] x 16-dword lines = 4 KB at the head of
// d_out, zeroed via hipMemsetAsync (graph-safe); fc_kernel fully overwrites
// d_out at the end.
// ---------------------------------------------------------------------------
extern "C" void kernel_launch(void* const* d_in, const int* in_sizes, int n_in,
                              void* d_out, int out_size, void* d_ws, size_t ws_size,
                              hipStream_t stream)
{
    (void)in_sizes; (void)n_in; (void)out_size; (void)ws_size;

    const float* x    = (const float*)d_in[0];
    const float* Wih0 = (const float*)d_in[1];
    const float* Whh0 = (const float*)d_in[2];
    const float* bih0 = (const float*)d_in[3];
    const float* bhh0 = (const float*)d_in[4];
    const float* Wih1 = (const float*)d_in[5];
    const float* Whh1 = (const float*)d_in[6];
    const float* bih1 = (const float*)d_in[7];
    const float* bhh1 = (const float*)d_in[8];
    const float* Wfc  = (const float*)d_in[9];
    const float* bfc  = (const float*)d_in[10];
    float* out = (float*)d_out;

    float* ws0 = (float*)d_ws;                    // [B][T][H] proj0 -> h0
    float* ws1 = ws0 + (size_t)B_ * T_ * H_;      // [B][T][H] h1
    unsigned int* bar = (unsigned int*)d_out;     // 2 x 32 x 16-dword lines

    hipMemsetAsync(bar, 0, 2 * TEAMS * 16 * sizeof(unsigned int), stream);

    dim3 gproj(B_ * T_ / 128, H_ / 128);   // (256, 4)

    gemm_bias_kernel<F_><<<gproj, 256, 0, stream>>>(x, Wih0, bih0, bhh0, ws0);
    fused_scan_kernel<<<TEAMS * TB, 256, 0, stream>>>(
        ws0, ws1, Whh0, Wih1, Whh1, bih1, bhh1, bar);
    fc_kernel<<<B_, 256, 0, stream>>>(ws1, Wfc, bfc, out);
}

// Round 12
// 2087.499 us; speedup vs baseline: 2.6669x; 2.6669x over previous
//
#include <hip/hip_runtime.h>
#include <cstddef>

#define B_ 256
#define T_ 128
#define F_ 256
#define H_ 512
#define C_ 10

#define TEAMS 32     // teams; team owns BS batch rows (2 blocks co-resident/CU)
#define TB    16     // blocks per team; member owns NS output columns
#define BS    8      // batch rows per team
#define NS    32     // n columns per member block

// ---------------------------------------------------------------------------
// GEMM (r9-proven): Cout[M,512] = A[M,K] @ W[512,K]^T + b1 + b2
// BM=BN=128, BK=16, 256 threads, 8x8 micro-tile.
// ---------------------------------------------------------------------------
template<int K>
__global__ __launch_bounds__(256, 2) void gemm_bias_kernel(
    const float* __restrict__ A, const float* __restrict__ W,
    const float* __restrict__ b1, const float* __restrict__ b2,
    float* __restrict__ Cout)
{
    __shared__ alignas(16) float As[16][132];
    __shared__ alignas(16) float Ws[16][132];

    const int tid = threadIdx.x;
    const int m0 = blockIdx.x * 128;
    const int n0 = blockIdx.y * 128;
    const int tx = tid & 15;
    const int ty = tid >> 4;

    float acc[8][8];
#pragma unroll
    for (int i = 0; i < 8; i++)
#pragma unroll
        for (int j = 0; j < 8; j++) acc[i][j] = 0.f;

    for (int k0 = 0; k0 < K; k0 += 16) {
#pragma unroll
        for (int i = 0; i < 2; i++) {
            int f = tid + 256 * i;
            int m = f >> 2, k4 = (f & 3) * 4;
            float4 v = *(const float4*)(A + (size_t)(m0 + m) * K + k0 + k4);
            As[k4 + 0][m] = v.x; As[k4 + 1][m] = v.y;
            As[k4 + 2][m] = v.z; As[k4 + 3][m] = v.w;
        }
#pragma unroll
        for (int i = 0; i < 2; i++) {
            int f = tid + 256 * i;
            int n = f >> 2, k4 = (f & 3) * 4;
            float4 v = *(const float4*)(W + (size_t)(n0 + n) * K + k0 + k4);
            Ws[k4 + 0][n] = v.x; Ws[k4 + 1][n] = v.y;
            Ws[k4 + 2][n] = v.z; Ws[k4 + 3][n] = v.w;
        }
        __syncthreads();

#pragma unroll
        for (int kk = 0; kk < 16; kk++) {
            float4 a0 = *(const float4*)&As[kk][ty * 8];
            float4 a1 = *(const float4*)&As[kk][ty * 8 + 4];
            float4 w0 = *(const float4*)&Ws[kk][tx * 8];
            float4 w1 = *(const float4*)&Ws[kk][tx * 8 + 4];
            float a[8] = {a0.x, a0.y, a0.z, a0.w, a1.x, a1.y, a1.z, a1.w};
            float w[8] = {w0.x, w0.y, w0.z, w0.w, w1.x, w1.y, w1.z, w1.w};
#pragma unroll
            for (int i = 0; i < 8; i++)
#pragma unroll
                for (int j = 0; j < 8; j++)
                    acc[i][j] = fmaf(a[i], w[j], acc[i][j]);
        }
        __syncthreads();
    }

    float bias[8];
#pragma unroll
    for (int j = 0; j < 8; j++) {
        int n = n0 + tx * 8 + j;
        bias[j] = b1[n] + b2[n];
    }
#pragma unroll
    for (int i = 0; i < 8; i++) {
        int m = m0 + ty * 8 + i;
        float4 v0 = {acc[i][0] + bias[0], acc[i][1] + bias[1],
                     acc[i][2] + bias[2], acc[i][3] + bias[3]};
        float4 v1 = {acc[i][4] + bias[4], acc[i][5] + bias[5],
                     acc[i][6] + bias[6], acc[i][7] + bias[7]};
        *(float4*)(Cout + (size_t)m * H_ + n0 + tx * 8)     = v0;
        *(float4*)(Cout + (size_t)m * H_ + n0 + tx * 8 + 4) = v1;
    }
}

// ---------------------------------------------------------------------------
// Team-parallel recurrent scan, fp32 (r9 base, wave-granular sync).
//
// Transport (r4/r5/r7/r9-proven): h via RELAXED agent-scope atomics on
// `data`. Sync primitive: monotonic fetch_add team counter (proven).
//
// Round-12 change — wave-granular wait/signal, 2 syncthreads/step not 4:
//  * WAIT: every wave polls the team counter itself (all 64 lanes load the
//    same dword -> single broadcast request, uniform loop exit), then
//    immediately stages its own share of hs. No block-wide pre-sync.
//  * SIGNAL: after the epilogue store each wave runs s_waitcnt(0) (its own
//    global stores drained), lane0-of-wave does an LDS atomicAdd; the 4th
//    wave of the block (old == 4t+3) issues the single global fetch_add.
//    Release chain: ds-add observed => that wave passed vmcnt(0) => its
//    h-stores are L2-visible before the global signal. Block signals when
//    its last wave drains — no barrier reconvergence on the signal path.
//  * Run-ahead safety: hs/red reads all precede our own block's signal,
//    and staging step t requires ALL 16 member signals (ours included),
//    so no wave can overwrite hs/red while any wave still reads them.
// ---------------------------------------------------------------------------
__global__ __launch_bounds__(256, 2) void scan_team_kernel(
    float* __restrict__ data, const float* __restrict__ Whh,
    unsigned int* __restrict__ bar, int gen0)
{
    __shared__ alignas(16) float hs[BS][H_];         // 16 KB
    __shared__ alignas(16) float red[16][BS][NS];    // 16 KB
    __shared__ unsigned int dsCnt;                   // wave-arrival counter

    const int tid  = threadIdx.x;
    const int team = blockIdx.x & 31;   // members congruent mod 32 -> same XCD
    const int mem  = blockIdx.x >> 5;   // 0..15
    const int b0   = team * BS;
    const int n0   = mem * NS;
    const int nl2  = tid & 15;          // col-pair index: cols n0+2*nl2, +1
    const int kg   = tid >> 4;          // 0..15, k-slice of 32
    const int n    = n0 + nl2 * 2;
    (void)mem;

    unsigned int* cnt = bar + team * 16;   // 64 B line per team

    if (tid == 0) dsCnt = 0;               // first __syncthreads publishes

    // ---- W slices (2 rows x 32 k) -> 16 float4, atomic-pinned (r9) ----
    float4 w0[8], w1[8];
    {
        const unsigned long long* q0 =
            (const unsigned long long*)(Whh + (size_t)n * H_ + (size_t)kg * 32);
        const unsigned long long* q1 =
            (const unsigned long long*)(Whh + (size_t)(n + 1) * H_ + (size_t)kg * 32);
#pragma unroll
        for (int j = 0; j < 8; j++) {
            union { unsigned long long q[2]; float4 f; } u;
            u.q[0] = __hip_atomic_load(q0 + 2 * j,     __ATOMIC_RELAXED,
                                       __HIP_MEMORY_SCOPE_AGENT);
            u.q[1] = __hip_atomic_load(q0 + 2 * j + 1, __ATOMIC_RELAXED,
                                       __HIP_MEMORY_SCOPE_AGENT);
            w0[j] = u.f;
            u.q[0] = __hip_atomic_load(q1 + 2 * j,     __ATOMIC_RELAXED,
                                       __HIP_MEMORY_SCOPE_AGENT);
            u.q[1] = __hip_atomic_load(q1 + 2 * j + 1, __ATOMIC_RELAXED,
                                       __HIP_MEMORY_SCOPE_AGENT);
            w1[j] = u.f;
        }
    }

    // proj/h pointer for this thread's single output per step
    float* pptr = data + ((size_t)(b0 + (tid >> 5)) * T_) * H_ + n0 + (tid & 31);
    float projv = *pptr;   // t=0 prefetch (owner-only line, normal cached load)

    for (int t = 0; t < T_; t++) {
        // ---- wave-granular wait + stage (no block pre-sync) ----
        if (gen0 + t > 0) {
            const unsigned tgt = (unsigned)TB * (unsigned)(gen0 + t);
            while (__hip_atomic_load(cnt, __ATOMIC_RELAXED,
                                     __HIP_MEMORY_SCOPE_AGENT) < tgt) {
                __builtin_amdgcn_s_sleep(2);
            }
        }
        if (t == 0) {
#pragma unroll
            for (int i = 0; i < 4; i++)
                ((float4*)hs)[tid + 256 * i] = float4{0.f, 0.f, 0.f, 0.f};
        } else {
            const float* sp = data + ((size_t)b0 * T_ + (t - 1)) * H_;
#pragma unroll
            for (int b = 0; b < BS; b++) {
                unsigned long long v = __hip_atomic_load(
                    (const unsigned long long*)(sp + (size_t)b * T_ * H_) + tid,
                    __ATOMIC_RELAXED, __HIP_MEMORY_SCOPE_AGENT);
                *((unsigned long long*)&hs[b][0] + tid) = v;
            }
        }
        __syncthreads();                                  // (B) hs ready

        // ---- k-partial dots, 2 cols/thread ----
        float p0[BS], p1[BS];
#pragma unroll
        for (int b = 0; b < BS; b++) { p0[b] = 0.f; p1[b] = 0.f; }
#pragma unroll
        for (int j = 0; j < 8; j++) {
            const float4 wa = w0[j];
            const float4 wb = w1[j];
            const int kb = kg * 32 + j * 4;
#pragma unroll
            for (int b = 0; b < BS; b++) {
                float4 hv = *(const float4*)&hs[b][kb];  // broadcast read
                p0[b] = fmaf(wa.x, hv.x, fmaf(wa.y, hv.y,
                        fmaf(wa.z, hv.z, fmaf(wa.w, hv.w, p0[b]))));
                p1[b] = fmaf(wb.x, hv.x, fmaf(wb.y, hv.y,
                        fmaf(wb.z, hv.z, fmaf(wb.w, hv.w, p1[b]))));
            }
        }
#pragma unroll
        for (int b = 0; b < BS; b++)
            *(float2*)&red[kg][b][nl2 * 2] = float2{p0[b], p1[b]};
        __syncthreads();                                  // (C) red ready

        // ---- epilogue: 1 output/thread ----
        {
            int bb = tid >> 5, n2 = tid & 31;
            float s = 0.f;
#pragma unroll
            for (int g = 0; g < 16; g++) s += red[g][bb][n2];
            float h = fmaxf(s + projv, 0.f);
            __hip_atomic_store(pptr, h,
                               __ATOMIC_RELAXED, __HIP_MEMORY_SCOPE_AGENT);
        }
        pptr += H_;

        // ---- wave-granular signal: drain own stores, LDS-arrive, last
        //      wave raises the global team counter ----
        __builtin_amdgcn_s_waitcnt(0);   // this wave's h-stores L2-visible
        if ((tid & 63) == 0) {
            unsigned old = atomicAdd(&dsCnt, 1u);        // LDS, monotonic
            if (old == 4u * (unsigned)t + 3u)            // 4th wave this step
                __hip_atomic_fetch_add(cnt, 1u,
                                       __ATOMIC_RELAXED, __HIP_MEMORY_SCOPE_AGENT);
        }
        if (t + 1 < T_) projv = *pptr;   // prefetch proj(t+1); rides the poll
    }
}

// ---------------------------------------------------------------------------
// FC head: out[b][c] = sum_i h1[b][i] * Wfc[c][i] + bfc[c]
// ---------------------------------------------------------------------------
__global__ __launch_bounds__(256) void fc_kernel(
    const float* __restrict__ Hl, const float* __restrict__ Wfc,
    const float* __restrict__ bfc, float* __restrict__ out)
{
    const int b = blockIdx.x;
    const int tid = threadIdx.x;
    const float* hb = Hl + (size_t)b * (T_ * H_);

    float acc[C_];
#pragma unroll
    for (int c = 0; c < C_; c++) acc[c] = 0.f;

    for (int i = tid * 4; i < T_ * H_; i += 256 * 4) {
        float4 hv = *(const float4*)(hb + i);
#pragma unroll
        for (int c = 0; c < C_; c++) {
            float4 wv = *(const float4*)(Wfc + (size_t)c * (T_ * H_) + i);
            acc[c] = fmaf(hv.x, wv.x, fmaf(hv.y, wv.y,
                     fmaf(hv.z, wv.z, fmaf(hv.w, wv.w, acc[c]))));
        }
    }

    __shared__ float red[4][C_];
#pragma unroll
    for (int c = 0; c < C_; c++) {
        float v = acc[c];
#pragma unroll
        for (int off = 32; off >= 1; off >>= 1) v += __shfl_xor(v, off, 64);
        if ((tid & 63) == 0) red[tid >> 6][c] = v;
    }
    __syncthreads();
    if (tid < C_) {
        float v = red[0][tid] + red[1][tid] + red[2][tid] + red[3][tid] + bfc[tid];
        out[(size_t)b * C_ + tid] = v;
    }
}

// ---------------------------------------------------------------------------
// Pipeline: proj0 GEMM -> scan0 -> proj1 GEMM -> scan1 -> FC.
// Team counters: 32 teams x 64 B lines in the first 2 KB of d_out (zeroed by
// hipMemsetAsync — graph-safe; fc_kernel fully overwrites d_out at the end).
// Monotonic across both scans: scan0 (gen0=0) signals 1..128; scan1
// (gen0=128) polls from TB*128 (already satisfied at t=0) and signals on.
// ---------------------------------------------------------------------------
extern "C" void kernel_launch(void* const* d_in, const int* in_sizes, int n_in,
                              void* d_out, int out_size, void* d_ws, size_t ws_size,
                              hipStream_t stream)
{
    (void)in_sizes; (void)n_in; (void)out_size; (void)ws_size;

    const float* x    = (const float*)d_in[0];
    const float* Wih0 = (const float*)d_in[1];
    const float* Whh0 = (const float*)d_in[2];
    const float* bih0 = (const float*)d_in[3];
    const float* bhh0 = (const float*)d_in[4];
    const float* Wih1 = (const float*)d_in[5];
    const float* Whh1 = (const float*)d_in[6];
    const float* bih1 = (const float*)d_in[7];
    const float* bhh1 = (const float*)d_in[8];
    const float* Wfc  = (const float*)d_in[9];
    const float* bfc  = (const float*)d_in[10];
    float* out = (float*)d_out;

    float* ws0 = (float*)d_ws;                    // [B][T][H] proj0 -> h0
    float* ws1 = ws0 + (size_t)B_ * T_ * H_;      // [B][T][H] proj1 -> h1
    unsigned int* bar = (unsigned int*)d_out;     // TEAMS x 16-dword lines

    hipMemsetAsync(bar, 0, TEAMS * 16 * sizeof(unsigned int), stream);

    dim3 gproj(B_ * T_ / 128, H_ / 128);   // (256, 4)

    gemm_bias_kernel<F_><<<gproj, 256, 0, stream>>>(x, Wih0, bih0, bhh0, ws0);
    scan_team_kernel<<<TEAMS * TB, 256, 0, stream>>>(ws0, Whh0, bar, 0);

    gemm_bias_kernel<H_><<<gproj, 256, 0, stream>>>(ws0, Wih1, bih1, bhh1, ws1);
    scan_team_kernel<<<TEAMS * TB, 256, 0, stream>>>(ws1, Whh1, bar, T_);

    fc_kernel<<<B_, 256, 0, stream>>>(ws1, Wfc, bfc, out);
}